// Round 2
// baseline (853.587 us; speedup 1.0000x reference)
//
#include <hip/hip_runtime.h>
#include <hip/hip_bf16.h>
#include <math.h>
#include <stdint.h>

// Problem constants
#define CCH   192      // channels
#define HWD   224      // H = W = 224
#define NWIN  8192     // 8 * 32 * 32 windows
#define NPIX  49       // 7*7 pixels per window
#define KDIM  192      // GEMM1 K
#define NHEAD 6
#define HD    32
#define ROWB  (KDIM * 2)   // 384 bytes per LDS row

typedef __bf16 bf16x8 __attribute__((ext_vector_type(8)));
typedef float f32x4 __attribute__((ext_vector_type(4)));

__device__ __forceinline__ uint16_t f2bf(float f) {
    uint32_t u = __builtin_bit_cast(uint32_t, f);
    u += 0x7FFFu + ((u >> 16) & 1u);   // RNE (inputs finite)
    return (uint16_t)(u >> 16);
}

// Convert W (384x192 f32) to bf16 pre-swizzled into MFMA B-fragment order:
// out[((ng*6 + kk)*4 + lg)*128 + lr*8 + e] = W[(ng*16+lr)*192 + kk*32+lg*8+e]
// so a wave's B-fragment load is 64 lanes x 16B contiguous (1 KB).
__global__ void wconv_kernel(const float* __restrict__ w,
                             uint16_t* __restrict__ wbf) {
    int o = blockIdx.x * 256 + threadIdx.x;
    if (o >= 384 * 192) return;
    int e  = o & 7;
    int t  = o >> 3;
    int lr = t & 15;  t >>= 4;
    int lg = t & 3;   t >>= 2;
    int kk = t % 6;
    int ng = t / 6;
    int col  = ng * 16 + lr;
    int kcol = kk * 32 + lg * 8 + e;
    wbf[o] = f2bf(w[col * KDIM + kcol]);
}

// One block per window. 256 threads = 4 waves. LDS = 2 x 49x192 bf16 = 36.8 KB
// -> 4 blocks/CU. Fragment rows >= 49 are clamped to 48 (garbage only feeds
// masked output rows/cols).
__global__ __launch_bounds__(256, 4)
void attn_win_kernel(const float* __restrict__ x,
                     const uint16_t* __restrict__ wbf,
                     const float* __restrict__ bq,
                     float* __restrict__ out) {
    __shared__ uint16_t ldsA[NPIX * KDIM];   // xw tile, later q
    __shared__ uint16_t ldsB[NPIX * KDIM];   // k

    const int tid  = threadIdx.x;
    const int wave = tid >> 6;
    const int l    = tid & 63;
    const int lg   = l >> 4;    // lane group 0..3
    const int lr   = l & 15;    // lane row/col 0..15

    // XCD-bijective remap: each XCD gets one contiguous batch image (8192 % 8 == 0)
    const int win = ((blockIdx.x & 7) << 10) | (blockIdx.x >> 3);
    const int b  = win >> 10;
    const int wh = (win >> 5) & 31;
    const int ww = win & 31;
    const int h0 = wh * 7, w0 = ww * 7;

    // ---- Phase 1: gather x window -> ldsA (bf16, XOR-swizzled rows)
    {
        const float* xb = x + (size_t)b * CCH * HWD * HWD;
        #pragma unroll 4
        for (int ii = 0; ii < 37; ++ii) {
            int idx = tid + ii * 256;
            if (idx < NPIX * CCH) {
                int c = idx / NPIX;
                int n = idx - c * NPIX;
                int r = n / 7, s = n - r * 7;
                float v = xb[((size_t)c * HWD + (h0 + r)) * HWD + (w0 + s)];
                int byte = (n * ROWB + c * 2) ^ ((n & 7) << 4);
                *(uint16_t*)((char*)ldsA + byte) = f2bf(v);
            }
        }
    }
    __syncthreads();

    // ---- Phase 2: GEMM1  qk[64 x 384] = xw @ W^T   (wave owns 96 cols)
    f32x4 acc[4][6];
    #pragma unroll
    for (int mt = 0; mt < 4; ++mt)
        #pragma unroll
        for (int nt = 0; nt < 6; ++nt)
            acc[mt][nt] = f32x4{0.f, 0.f, 0.f, 0.f};

    #pragma unroll
    for (int kk = 0; kk < 6; ++kk) {
        bf16x8 afr[4];
        #pragma unroll
        for (int mt = 0; mt < 4; ++mt) {
            int row = mt * 16 + lr;
            if (row > 48) row = 48;                       // clamp: no pad rows
            int byte = (row * ROWB + kk * 64 + lg * 16) ^ ((row & 7) << 4);
            afr[mt] = *(const bf16x8*)((const char*)ldsA + byte);
        }
        #pragma unroll
        for (int nt = 0; nt < 6; ++nt) {
            int ng = wave * 6 + nt;
            bf16x8 bfr = *(const bf16x8*)(wbf + ((ng * 6 + kk) * 4 + lg) * 128 + lr * 8);
            #pragma unroll
            for (int mt = 0; mt < 4; ++mt)
                acc[mt][nt] = __builtin_amdgcn_mfma_f32_16x16x32_bf16(
                    afr[mt], bfr, acc[mt][nt], 0, 0, 0);
        }
    }
    __syncthreads();   // all GEMM1 reads of ldsA done before q overwrites it

    // ---- Phase 3: bias (+scale for q), store q -> ldsA, k -> ldsB as bf16
    {
        const float scale = 0.17677669529663687f;  // 32^-0.5
        const bool isq = (wave < 2);
        const float mul = isq ? scale : 1.0f;
        uint16_t* dst = isq ? ldsA : ldsB;
        #pragma unroll
        for (int nt = 0; nt < 6; ++nt) {
            int col = wave * 96 + nt * 16 + lr;
            float bias = bq[col];
            int jj = isq ? col : (col - 192);
            #pragma unroll
            for (int mt = 0; mt < 4; ++mt) {
                #pragma unroll
                for (int r = 0; r < 4; ++r) {
                    int row = mt * 16 + lg * 4 + r;
                    if (row < NPIX) {
                        float v = (acc[mt][nt][r] + bias) * mul;
                        int byte = (row * ROWB + jj * 2) ^ ((row & 7) << 4);
                        *(uint16_t*)((char*)dst + byte) = f2bf(v);
                    }
                }
            }
        }
    }
    __syncthreads();

    // ---- Phase 4: GEMM2 (q_h @ k_h^T) + softmax + store.
    // 24 (head, mtile) pairs, 6 per wave.
    float* outw = out + (size_t)win * (NHEAD * NPIX * NPIX);
    #pragma unroll
    for (int i = 0; i < 6; ++i) {
        const int p  = wave * 6 + i;
        const int h  = p >> 2;
        const int mt = p & 3;

        int arow = mt * 16 + lr;
        if (arow > 48) arow = 48;                          // clamp
        const int abyte = (arow * ROWB + h * 64 + lg * 16) ^ ((arow & 7) << 4);
        const bf16x8 afr = *(const bf16x8*)((const char*)ldsA + abyte);

        f32x4 pacc[4];
        #pragma unroll
        for (int nt2 = 0; nt2 < 4; ++nt2) {
            int brow = nt2 * 16 + lr;
            if (brow > 48) brow = 48;                      // clamp
            int bbyte = (brow * ROWB + h * 64 + lg * 16) ^ ((brow & 7) << 4);
            bf16x8 bfr = *(const bf16x8*)((const char*)ldsB + bbyte);
            pacc[nt2] = __builtin_amdgcn_mfma_f32_16x16x32_bf16(
                afr, bfr, f32x4{0.f, 0.f, 0.f, 0.f}, 0, 0, 0);
        }

        // softmax over cols. Row n = mt*16 + lg*4 + r; lane holds cols nt2*16+lr.
        #pragma unroll
        for (int r = 0; r < 4; ++r) {
            float v[4];
            #pragma unroll
            for (int nt2 = 0; nt2 < 4; ++nt2) {
                int cc = nt2 * 16 + lr;
                v[nt2] = (cc < NPIX) ? pacc[nt2][r] : -INFINITY;
            }
            float m = fmaxf(fmaxf(v[0], v[1]), fmaxf(v[2], v[3]));
            #pragma unroll
            for (int s = 1; s < 16; s <<= 1)
                m = fmaxf(m, __shfl_xor(m, s, 64));

            float e[4];
            float sum = 0.f;
            #pragma unroll
            for (int nt2 = 0; nt2 < 4; ++nt2) {
                e[nt2] = __expf(v[nt2] - m);   // exp(-inf)=0 for masked cols
                sum += e[nt2];
            }
            #pragma unroll
            for (int s = 1; s < 16; s <<= 1)
                sum += __shfl_xor(sum, s, 64);
            float inv = 1.0f / sum;

            int n = mt * 16 + lg * 4 + r;
            if (n < NPIX) {
                float* orow = outw + (size_t)h * (NPIX * NPIX) + (size_t)n * NPIX;
                #pragma unroll
                for (int nt2 = 0; nt2 < 4; ++nt2) {
                    int cc = nt2 * 16 + lr;
                    if (cc < NPIX) orow[cc] = e[nt2] * inv;
                }
            }
        }
    }
}

extern "C" void kernel_launch(void* const* d_in, const int* in_sizes, int n_in,
                              void* d_out, int out_size, void* d_ws, size_t ws_size,
                              hipStream_t stream) {
    const float* x  = (const float*)d_in[0];
    const float* W  = (const float*)d_in[1];
    const float* bq = (const float*)d_in[2];
    float* out = (float*)d_out;
    uint16_t* wbf = (uint16_t*)d_ws;   // 384*192 bf16 = 147456 B (swizzled)

    wconv_kernel<<<(384 * 192 + 255) / 256, 256, 0, stream>>>(W, wbf);
    attn_win_kernel<<<NWIN, 256, 0, stream>>>(x, wbf, bq, out);
}

// Round 3
// 534.653 us; speedup vs baseline: 1.5965x; 1.5965x over previous
//
#include <hip/hip_runtime.h>
#include <hip/hip_bf16.h>
#include <math.h>
#include <stdint.h>

// Problem constants
#define CCH   192      // channels
#define HWD   224      // H = W = 224
#define NWIN  8192     // 8 * 32 * 32 windows
#define NPIX  49       // 7*7 pixels per window
#define KDIM  192      // GEMM1 K
#define NHEAD 6
#define HD    32
#define ROWB  (KDIM * 2)   // 384 bytes per LDS row

typedef __bf16 bf16x8 __attribute__((ext_vector_type(8)));
typedef float f32x4 __attribute__((ext_vector_type(4)));

__device__ __forceinline__ uint16_t f2bf(float f) {
    uint32_t u = __builtin_bit_cast(uint32_t, f);
    u += 0x7FFFu + ((u >> 16) & 1u);   // RNE (inputs finite)
    return (uint16_t)(u >> 16);
}

// Convert W (384x192 f32) to bf16 pre-swizzled into MFMA B-fragment order:
// out[((ng*6 + kk)*4 + lg)*128 + lr*8 + e] = W[(ng*16+lr)*192 + kk*32+lg*8+e]
// so a wave's B-fragment load is 64 lanes x 16B contiguous (1 KB).
__global__ void wconv_kernel(const float* __restrict__ w,
                             uint16_t* __restrict__ wbf) {
    int o = blockIdx.x * 256 + threadIdx.x;
    if (o >= 384 * 192) return;
    int e  = o & 7;
    int t  = o >> 3;
    int lr = t & 15;  t >>= 4;
    int lg = t & 3;   t >>= 2;
    int kk = t % 6;
    int ng = t / 6;
    int col  = ng * 16 + lr;
    int kcol = kk * 32 + lg * 8 + e;
    wbf[o] = f2bf(w[col * KDIM + kcol]);
}

// One block per window. 256 threads = 4 waves.
// LDS = q(18816) + k(18816) + S-stage(9604) = 47.2 KB -> 3 blocks/CU.
__global__ __launch_bounds__(256, 3)
void attn_win_kernel(const float* __restrict__ x,
                     const uint16_t* __restrict__ wbf,
                     const float* __restrict__ bq,
                     float* __restrict__ out) {
    __shared__ uint16_t ldsA[NPIX * KDIM];   // xw tile, later q
    __shared__ uint16_t ldsB[NPIX * KDIM];   // k
    __shared__ float    ldsS[NPIX * NPIX];   // softmax panel stage

    const int tid  = threadIdx.x;
    const int wave = tid >> 6;
    const int l    = tid & 63;
    const int lg   = l >> 4;    // lane group 0..3
    const int lr   = l & 15;    // lane row/col 0..15

    // XCD-bijective remap: each XCD gets one contiguous batch image (8192 % 8 == 0)
    const int win = ((blockIdx.x & 7) << 10) | (blockIdx.x >> 3);
    const int b  = win >> 10;
    const int wh = (win >> 5) & 31;
    const int ww = win & 31;
    const int h0 = wh * 7, w0 = ww * 7;

    // ---- Phase 1: gather x window -> ldsA (bf16, XOR-swizzled rows)
    {
        const float* xb = x + (size_t)b * CCH * HWD * HWD;
        #pragma unroll 4
        for (int ii = 0; ii < 37; ++ii) {
            int idx = tid + ii * 256;
            if (idx < NPIX * CCH) {
                int c = idx / NPIX;
                int n = idx - c * NPIX;
                int r = n / 7, s = n - r * 7;
                float v = xb[((size_t)c * HWD + (h0 + r)) * HWD + (w0 + s)];
                int byte = (n * ROWB + c * 2) ^ ((n & 7) << 4);
                *(uint16_t*)((char*)ldsA + byte) = f2bf(v);
            }
        }
    }
    __syncthreads();

    // ---- Phase 2: GEMM1  qk[64 x 384] = xw @ W^T   (wave owns 96 cols)
    f32x4 acc[4][6];
    #pragma unroll
    for (int mt = 0; mt < 4; ++mt)
        #pragma unroll
        for (int nt = 0; nt < 6; ++nt)
            acc[mt][nt] = f32x4{0.f, 0.f, 0.f, 0.f};

    #pragma unroll
    for (int kk = 0; kk < 6; ++kk) {
        bf16x8 afr[4];
        #pragma unroll
        for (int mt = 0; mt < 4; ++mt) {
            int row = mt * 16 + lr;
            if (row > 48) row = 48;                       // clamp: no pad rows
            int byte = (row * ROWB + kk * 64 + lg * 16) ^ ((row & 7) << 4);
            afr[mt] = *(const bf16x8*)((const char*)ldsA + byte);
        }
        #pragma unroll
        for (int nt = 0; nt < 6; ++nt) {
            int ng = wave * 6 + nt;
            bf16x8 bfr = *(const bf16x8*)(wbf + ((ng * 6 + kk) * 4 + lg) * 128 + lr * 8);
            #pragma unroll
            for (int mt = 0; mt < 4; ++mt)
                acc[mt][nt] = __builtin_amdgcn_mfma_f32_16x16x32_bf16(
                    afr[mt], bfr, acc[mt][nt], 0, 0, 0);
        }
    }
    __syncthreads();   // all GEMM1 reads of ldsA done before q overwrites it

    // ---- Phase 3: bias (+scale for q), store q -> ldsA, k -> ldsB as bf16
    {
        const float scale = 0.17677669529663687f;  // 32^-0.5
        const bool isq = (wave < 2);
        const float mul = isq ? scale : 1.0f;
        uint16_t* dst = isq ? ldsA : ldsB;
        #pragma unroll
        for (int nt = 0; nt < 6; ++nt) {
            int col = wave * 96 + nt * 16 + lr;
            float bias = bq[col];
            int jj = isq ? col : (col - 192);
            #pragma unroll
            for (int mt = 0; mt < 4; ++mt) {
                #pragma unroll
                for (int r = 0; r < 4; ++r) {
                    int row = mt * 16 + lg * 4 + r;
                    if (row < NPIX) {
                        float v = (acc[mt][nt][r] + bias) * mul;
                        int byte = (row * ROWB + jj * 2) ^ ((row & 7) << 4);
                        *(uint16_t*)((char*)dst + byte) = f2bf(v);
                    }
                }
            }
        }
    }
    __syncthreads();

    // ---- Phase 4: per head: S = q_h @ k_h^T, softmax, stage panel in LDS,
    // then stream the 49x49 panel to global as line-complete coalesced stores.
    // Wave w computes output rows [16w, 16w+16) (rows >= 49 are garbage/masked).
    float* outw = out + (size_t)win * (NHEAD * NPIX * NPIX);
    for (int h = 0; h < NHEAD; ++h) {
        int arow = wave * 16 + lr;
        if (arow > 48) arow = 48;                          // clamp
        const int abyte = (arow * ROWB + h * 64 + lg * 16) ^ ((arow & 7) << 4);
        const bf16x8 afr = *(const bf16x8*)((const char*)ldsA + abyte);

        f32x4 pacc[4];
        #pragma unroll
        for (int nt2 = 0; nt2 < 4; ++nt2) {
            int brow = nt2 * 16 + lr;
            if (brow > 48) brow = 48;                      // clamp
            int bbyte = (brow * ROWB + h * 64 + lg * 16) ^ ((brow & 7) << 4);
            bf16x8 bfr = *(const bf16x8*)((const char*)ldsB + bbyte);
            pacc[nt2] = __builtin_amdgcn_mfma_f32_16x16x32_bf16(
                afr, bfr, f32x4{0.f, 0.f, 0.f, 0.f}, 0, 0, 0);
        }

        // softmax over cols. Row n = wave*16 + lg*4 + r; lane holds cols nt2*16+lr.
        #pragma unroll
        for (int r = 0; r < 4; ++r) {
            float v[4];
            #pragma unroll
            for (int nt2 = 0; nt2 < 4; ++nt2) {
                int cc = nt2 * 16 + lr;
                v[nt2] = (cc < NPIX) ? pacc[nt2][r] : -INFINITY;
            }
            float m = fmaxf(fmaxf(v[0], v[1]), fmaxf(v[2], v[3]));
            #pragma unroll
            for (int s = 1; s < 16; s <<= 1)
                m = fmaxf(m, __shfl_xor(m, s, 64));

            float e[4];
            float sum = 0.f;
            #pragma unroll
            for (int nt2 = 0; nt2 < 4; ++nt2) {
                e[nt2] = __expf(v[nt2] - m);   // exp(-inf)=0 for masked cols
                sum += e[nt2];
            }
            #pragma unroll
            for (int s = 1; s < 16; s <<= 1)
                sum += __shfl_xor(sum, s, 64);
            float inv = 1.0f / sum;

            int n = wave * 16 + lg * 4 + r;
            if (n < NPIX) {
                #pragma unroll
                for (int nt2 = 0; nt2 < 4; ++nt2) {
                    int cc = nt2 * 16 + lr;
                    if (cc < NPIX) ldsS[n * NPIX + cc] = e[nt2] * inv;
                }
            }
        }
        __syncthreads();   // panel complete in LDS

        // stream panel: 2401 floats, coalesced, lines complete immediately
        float* oph = outw + h * (NPIX * NPIX);
        #pragma unroll
        for (int it = 0; it < 10; ++it) {
            int idx = it * 256 + tid;
            if (idx < NPIX * NPIX) oph[idx] = ldsS[idx];
        }
        __syncthreads();   // before next head reuses ldsS
    }
}

extern "C" void kernel_launch(void* const* d_in, const int* in_sizes, int n_in,
                              void* d_out, int out_size, void* d_ws, size_t ws_size,
                              hipStream_t stream) {
    const float* x  = (const float*)d_in[0];
    const float* W  = (const float*)d_in[1];
    const float* bq = (const float*)d_in[2];
    float* out = (float*)d_out;
    uint16_t* wbf = (uint16_t*)d_ws;   // 384*192 bf16 = 147456 B (swizzled)

    wconv_kernel<<<(384 * 192 + 255) / 256, 256, 0, stream>>>(W, wbf);
    attn_win_kernel<<<NWIN, 256, 0, stream>>>(x, wbf, bq, out);
}

// Round 4
// 336.929 us; speedup vs baseline: 2.5334x; 1.5868x over previous
//
#include <hip/hip_runtime.h>
#include <hip/hip_bf16.h>
#include <math.h>
#include <stdint.h>

// Problem constants
#define CCH   192      // channels
#define HWD   224      // H = W = 224
#define NWIN  8192     // 8 * 32 * 32 windows
#define NPIX  49       // 7*7 pixels per window
#define KDIM  192      // GEMM1 K
#define NHEAD 6
#define ROWB  (KDIM * 2)   // 384 bytes per LDS row

typedef __bf16 bf16x8 __attribute__((ext_vector_type(8)));
typedef __bf16 bf16x2 __attribute__((ext_vector_type(2)));
typedef float  f32x4  __attribute__((ext_vector_type(4)));

// Convert W (384x192 f32) to bf16 pre-swizzled into MFMA B-fragment order:
// out[((ng*6 + kk)*4 + lg)*128 + lr*8 + e] = W[(ng*16+lr)*192 + kk*32+lg*8+e]
__global__ void wconv_kernel(const float* __restrict__ w,
                             uint16_t* __restrict__ wbf) {
    int o = blockIdx.x * 256 + threadIdx.x;
    if (o >= 384 * 192) return;
    int e  = o & 7;
    int t  = o >> 3;
    int lr = t & 15;  t >>= 4;
    int lg = t & 3;   t >>= 2;
    int kk = t % 6;
    int ng = t / 6;
    int col  = ng * 16 + lr;
    int kcol = kk * 32 + lg * 8 + e;
    __bf16 v = (__bf16)w[col * KDIM + kcol];
    wbf[o] = __builtin_bit_cast(uint16_t, v);
}

// One block per window. 512 threads = 8 waves. LDS = 2 x 49x192 bf16 = 36.8 KB.
// 2 blocks/CU (16 waves/CU), VGPR budget 128.
__global__ __launch_bounds__(512, 4)
void attn_win_kernel(const float* __restrict__ x,
                     const uint16_t* __restrict__ wbf,
                     const float* __restrict__ bq,
                     float* __restrict__ out) {
    __shared__ uint16_t ldsA[NPIX * KDIM];   // xw tile, later q
    __shared__ uint16_t ldsB[NPIX * KDIM];   // k

    const int tid  = threadIdx.x;
    const int wave = tid >> 6;   // 0..7
    const int l    = tid & 63;
    const int lg   = l >> 4;     // 0..3
    const int lr   = l & 15;     // 0..15

    // XCD-bijective remap: each XCD gets one contiguous batch image (8192 % 8 == 0)
    const int win = ((blockIdx.x & 7) << 10) | (blockIdx.x >> 3);
    const int b   = win >> 10;
    const int wh  = (win >> 5) & 31;
    const int ww  = win & 31;
    const int h0 = wh * 7, w0 = ww * 7;

    // ---- Phase 1: gather x window -> ldsA (bf16, XOR-swizzled rows).
    // lane = pixel (49 active), wave owns 24 channels; pack 2 chans per u32 write.
    if (l < NPIX) {
        int r = (l * 37) >> 8;          // l / 7 for l in [0,49)
        int s = l - r * 7;
        const float* xp = x + (size_t)(b * CCH + wave * 24) * (HWD * HWD)
                            + (h0 + r) * HWD + (w0 + s);
        const uint32_t rb  = (uint32_t)(l * ROWB + wave * 24 * 2);
        const uint32_t swz = (uint32_t)((l & 7) << 4);
        #pragma unroll 4
        for (int c = 0; c < 24; c += 2) {
            float v0 = xp[0];
            float v1 = xp[HWD * HWD];
            xp += 2 * (HWD * HWD);
            bf16x2 p = { (__bf16)v0, (__bf16)v1 };
            uint32_t byte = (rb + (uint32_t)(c * 2)) ^ swz;
            *(uint32_t*)((char*)ldsA + byte) = __builtin_bit_cast(uint32_t, p);
        }
    }
    __syncthreads();

    // ---- Phase 2: GEMM1  qk[64 x 384] = xw @ W^T   (wave owns 48 W-cols)
    f32x4 acc[4][3];
    #pragma unroll
    for (int mt = 0; mt < 4; ++mt)
        #pragma unroll
        for (int nt = 0; nt < 3; ++nt)
            acc[mt][nt] = f32x4{0.f, 0.f, 0.f, 0.f};

    #pragma unroll
    for (int kk = 0; kk < 6; ++kk) {
        bf16x8 afr[4];
        #pragma unroll
        for (int mt = 0; mt < 4; ++mt) {
            int row = mt * 16 + lr;
            if (row > 48) row = 48;                       // clamp: no pad rows
            int byte = (row * ROWB + kk * 64 + lg * 16) ^ ((row & 7) << 4);
            afr[mt] = *(const bf16x8*)((const char*)ldsA + byte);
        }
        #pragma unroll
        for (int nt = 0; nt < 3; ++nt) {
            int ng = wave * 3 + nt;
            bf16x8 bfr = *(const bf16x8*)(wbf + ((ng * 6 + kk) * 4 + lg) * 128 + lr * 8);
            #pragma unroll
            for (int mt = 0; mt < 4; ++mt)
                acc[mt][nt] = __builtin_amdgcn_mfma_f32_16x16x32_bf16(
                    afr[mt], bfr, acc[mt][nt], 0, 0, 0);
        }
    }
    __syncthreads();   // all GEMM1 reads of ldsA done before q overwrites it

    // ---- Phase 3: bias (+scale*log2e for q), q -> ldsA, k -> ldsB (bf16)
    {
        const float mulq = 0.2550348616845977f;  // 32^-0.5 * log2(e)
        const bool isq = (wave < 4);
        const float mul = isq ? mulq : 1.0f;
        uint16_t* dst = isq ? ldsA : ldsB;
        #pragma unroll
        for (int nt = 0; nt < 3; ++nt) {
            int colW = wave * 48 + nt * 16 + lr;    // 0..383
            float bias = bq[colW];
            int jj = isq ? colW : (colW - 192);
            #pragma unroll
            for (int mt = 0; mt < 4; ++mt) {
                #pragma unroll
                for (int r = 0; r < 4; ++r) {
                    int row = mt * 16 + lg * 4 + r;
                    if (row < NPIX) {
                        __bf16 bv = (__bf16)((acc[mt][nt][r] + bias) * mul);
                        *(__bf16*)((char*)dst +
                            ((row * ROWB + jj * 2) ^ ((row & 7) << 4))) = bv;
                    }
                }
            }
        }
    }
    __syncthreads();

    // ---- Phase 4: swapped-operand GEMM2 + lane-local softmax + direct stores.
    // mfma(K_tile, Q_tile): D col = q-row, D row = k-idx. Lane (lg,lr) of wave
    // with q-tile qt holds S[qrow = qt*16+lr][k = nt2*16 + lg*4 + r].
    // Wave -> (q-tile, head set): qt = wave&3, heads {wave>>2} + {0,2,4}.
    float* outw = out + (size_t)win * (NHEAD * NPIX * NPIX);
    const int qt    = wave & 3;
    const int hbase = wave >> 2;
    const int qrow  = qt * 16 + lr;
    const int qrc   = qrow > 48 ? 48 : qrow;            // clamped read row
    const uint32_t qswz = (uint32_t)((qrc & 7) << 4);

    for (int hi = 0; hi < 3; ++hi) {
        const int h = hbase + hi * 2;
        const bf16x8 qfr = *(const bf16x8*)((const char*)ldsA +
            (((uint32_t)(qrc * ROWB + h * 64 + lg * 16)) ^ qswz));

        float v[16];
        #pragma unroll
        for (int nt2 = 0; nt2 < 4; ++nt2) {
            int krow = nt2 * 16 + lr;
            if (krow > 48) krow = 48;                   // clamp (broadcast, free)
            const bf16x8 kfr = *(const bf16x8*)((const char*)ldsB +
                (((uint32_t)(krow * ROWB + h * 64 + lg * 16)) ^ ((krow & 7) << 4)));
            f32x4 p = __builtin_amdgcn_mfma_f32_16x16x32_bf16(
                kfr, qfr, f32x4{0.f, 0.f, 0.f, 0.f}, 0, 0, 0);
            #pragma unroll
            for (int r = 0; r < 4; ++r) {
                int k = nt2 * 16 + lg * 4 + r;
                v[nt2 * 4 + r] = (k < NPIX) ? p[r] : -INFINITY;
            }
        }

        // row softmax: 16 in-lane values + 2 cross-lane steps (lanes l^16, l^32)
        float m = v[0];
        #pragma unroll
        for (int i = 1; i < 16; ++i) m = fmaxf(m, v[i]);
        m = fmaxf(m, __shfl_xor(m, 16, 64));
        m = fmaxf(m, __shfl_xor(m, 32, 64));

        float sum = 0.f;
        #pragma unroll
        for (int i = 0; i < 16; ++i) {
            v[i] = exp2f(v[i] - m);    // logits already in log2 domain
            sum += v[i];
        }
        sum += __shfl_xor(sum, 16, 64);
        sum += __shfl_xor(sum, 32, 64);
        const float inv = __fdividef(1.0f, sum);

        if (qrow < NPIX) {
            float* orow = outw + h * (NPIX * NPIX) + qrow * NPIX;
            #pragma unroll
            for (int nt2 = 0; nt2 < 3; ++nt2)
                #pragma unroll
                for (int r = 0; r < 4; ++r)
                    orow[nt2 * 16 + lg * 4 + r] = v[nt2 * 4 + r] * inv;
            if (lg == 0) orow[48] = v[12] * inv;
        }
    }
}

extern "C" void kernel_launch(void* const* d_in, const int* in_sizes, int n_in,
                              void* d_out, int out_size, void* d_ws, size_t ws_size,
                              hipStream_t stream) {
    const float* x  = (const float*)d_in[0];
    const float* W  = (const float*)d_in[1];
    const float* bq = (const float*)d_in[2];
    float* out = (float*)d_out;
    uint16_t* wbf = (uint16_t*)d_ws;   // 384*192 bf16 = 147456 B (swizzled)

    wconv_kernel<<<(384 * 192 + 255) / 256, 256, 0, stream>>>(W, wbf);
    attn_win_kernel<<<NWIN, 512, 0, stream>>>(x, wbf, bq, out);
}